// Round 19
// baseline (101.906 us; speedup 1.0000x reference)
//
#include <hip/hip_runtime.h>

// GradientConv: out[tgt, c*2+d] += ew[e,d] * (x[src,c] - x[tgt,c])
// B=1, N=50000, C=128, E=800000, D=2
//
// Pipeline (3 dispatches):
//   1) memset counts
//   2) k_prep: fused {XCD-partitioned append, 4x-unrolled two-phase loop:
//      issue up to 8 independent atomicAdds, THEN the dependent stores ->
//      ~8 atomic chains in flight per thread (latency hiding)} +
//      {x->bf16 cvt (remaining blocks)}
//   3) k_gather5: one wave per node, 32-bit indexing, 4-tier unroll,
//        out[t] = sum_e w_e (x) xb[src_e] - (sum_e w_e) (x) x[t]
//      rec load clamped to lanes 0-31; overflow folded in-register (exact).
// Fallbacks: f32 CAP=64 bucket path, atomics.

#define CAP 32
#define OVF_CAP 65536
#define NPART 8
#define NAPP 3328  // append blocks: 8 partitions x 416

typedef unsigned short u16;
typedef unsigned int u32;

__device__ __forceinline__ u16 f2bf(float f) {
  u32 u = __float_as_uint(f);
  return (u16)((u + 0x7FFFu + ((u >> 16) & 1u)) >> 16);
}
__device__ __forceinline__ float bf2f(u16 v) {
  return __uint_as_float(((u32)v) << 16);
}

// ---------- fused append (XCD-partitioned, pipelined atomics) + cvt ----------
__global__ __launch_bounds__(256) void k_prep(const int* __restrict__ edges,
                                              const float* __restrict__ ew,
                                              const float* __restrict__ x,
                                              int* __restrict__ counts,
                                              int4* __restrict__ rec,
                                              int* __restrict__ ovfcnt,
                                              int4* __restrict__ ovflist,
                                              u16* __restrict__ xb,
                                              int E, int N, int total4) {
  if (blockIdx.x < NAPP) {
    // ---- append: partition = blockIdx&7 tracks XCD round-robin ----
    const int part = blockIdx.x & (NPART - 1);
    const int bidx = blockIdx.x >> 3;
    const int nblk = NAPP >> 3;
    const int lo = (int)((long long)part * N / NPART);
    const int hi = (int)((long long)(part + 1) * N / NPART);
    const int npairs = E >> 1;  // E even (guarded on host)
    const int stride = nblk * blockDim.x;
    const int tid = bidx * blockDim.x + threadIdx.x;

    int i = tid;
    // ---- 4x-unrolled main loop: 8 edge slots, two-phase ----
    for (; i + 3 * stride < npairs; i += 4 * stride) {
      int tg[8], sr[8];
      float wx[8], wy[8];
      bool v[8];
      #pragma unroll
      for (int k = 0; k < 4; ++k) {
        const int idx = i + k * stride;
        const int4 p = reinterpret_cast<const int4*>(edges)[idx];  // t0,s0,t1,s1
        const bool in0 = (p.x >= lo) & (p.x < hi);
        const bool in1 = (p.z >= lo) & (p.z < hi);
        v[2 * k] = in0; v[2 * k + 1] = in1;
        tg[2 * k] = p.x; sr[2 * k] = p.y;
        tg[2 * k + 1] = p.z; sr[2 * k + 1] = p.w;
        if (in0 | in1) {
          const float4 w = reinterpret_cast<const float4*>(ew)[idx];
          wx[2 * k] = w.x; wy[2 * k] = w.y;
          wx[2 * k + 1] = w.z; wy[2 * k + 1] = w.w;
        }
      }
      // phase 1: issue all atomics (independent -> overlap in flight)
      int pos[8];
      #pragma unroll
      for (int k = 0; k < 8; ++k) {
        if (v[k]) pos[k] = atomicAdd(&counts[tg[k]], 1);
      }
      // phase 2: dependent stores
      #pragma unroll
      for (int k = 0; k < 8; ++k) {
        if (v[k]) {
          if (pos[k] < CAP) {
            int4 r;
            r.x = sr[k]; r.y = __float_as_int(wx[k]);
            r.z = __float_as_int(wy[k]); r.w = 0;
            rec[tg[k] * CAP + pos[k]] = r;
          } else {
            const int op = atomicAdd(ovfcnt, 1);
            if (op < OVF_CAP) {
              int4 r;
              r.x = tg[k]; r.y = sr[k];
              r.z = __float_as_int(wx[k]); r.w = __float_as_int(wy[k]);
              ovflist[op] = r;
            }
          }
        }
      }
    }
    // ---- tail ----
    for (; i < npairs; i += stride) {
      const int4 p = reinterpret_cast<const int4*>(edges)[i];
      const bool in0 = (p.x >= lo) & (p.x < hi);
      const bool in1 = (p.z >= lo) & (p.z < hi);
      if (in0 | in1) {
        const float4 w = reinterpret_cast<const float4*>(ew)[i];
        if (in0) {
          const int pos = atomicAdd(&counts[p.x], 1);
          if (pos < CAP) {
            int4 r; r.x = p.y; r.y = __float_as_int(w.x);
            r.z = __float_as_int(w.y); r.w = 0;
            rec[p.x * CAP + pos] = r;
          } else {
            const int op = atomicAdd(ovfcnt, 1);
            if (op < OVF_CAP) {
              int4 r; r.x = p.x; r.y = p.y;
              r.z = __float_as_int(w.x); r.w = __float_as_int(w.y);
              ovflist[op] = r;
            }
          }
        }
        if (in1) {
          const int pos = atomicAdd(&counts[p.z], 1);
          if (pos < CAP) {
            int4 r; r.x = p.w; r.y = __float_as_int(w.z);
            r.z = __float_as_int(w.w); r.w = 0;
            rec[p.z * CAP + pos] = r;
          } else {
            const int op = atomicAdd(ovfcnt, 1);
            if (op < OVF_CAP) {
              int4 r; r.x = p.z; r.y = p.w;
              r.z = __float_as_int(w.z); r.w = __float_as_int(w.w);
              ovflist[op] = r;
            }
          }
        }
      }
    }
  } else {
    // ---- cvt: grid-stride over x in float4 units ----
    const int nb = gridDim.x - NAPP;
    const int stride = nb * blockDim.x;
    for (int i = (blockIdx.x - NAPP) * blockDim.x + threadIdx.x; i < total4;
         i += stride) {
      const float4 v = reinterpret_cast<const float4*>(x)[i];
      ushort4 o;
      o.x = f2bf(v.x); o.y = f2bf(v.y); o.z = f2bf(v.z); o.w = f2bf(v.w);
      reinterpret_cast<ushort4*>(xb)[i] = o;
    }
  }
}

#define ACC8(X0, X1, X2, X3, WX, WY)                    \
  a0 = fmaf((WX), (X0), a0); a1 = fmaf((WY), (X0), a1); \
  a2 = fmaf((WX), (X1), a2); a3 = fmaf((WY), (X1), a3); \
  a4 = fmaf((WX), (X2), a4); a5 = fmaf((WY), (X2), a5); \
  a6 = fmaf((WX), (X3), a6); a7 = fmaf((WY), (X3), a7);

// One wave per node; c=lane&31 covers channels 4c..4c+3; half-wave processes
// even/odd edge indices. ALL indexing 32-bit -> saddr+voffset loads.
__global__ __launch_bounds__(256) void k_gather5(const float* __restrict__ x,
                                                 const u16* __restrict__ xb,
                                                 const int* __restrict__ counts,
                                                 const int4* __restrict__ rec,
                                                 const int* __restrict__ ovfcnt,
                                                 const int4* __restrict__ ovflist,
                                                 float* __restrict__ out, int n) {
  const int lane = threadIdx.x & 63;
  const int node = (blockIdx.x * blockDim.x + threadIdx.x) >> 6;
  if (node >= n) return;
  const int c = lane & 31;
  const int half = lane >> 5;
  const int c4 = 4 * c;

  const int cnt = counts[node];
  const int deg = min(cnt, CAP);

  // xt early (independent f32 load for exact -sum(w)*x[t]).
  const float4 xt = *reinterpret_cast<const float4*>(x + (node << 7) + c4);

  int rsrc = 0;
  float rwx = 0.f, rwy = 0.f;
  if (deg > 0) {
    // shfl only reads lanes<32 (npair<=16): lanes 32-63 duplicate 0-31.
    const int li = min(lane & 31, deg - 1);
    const int4 r = rec[(node << 5) + li];  // CAP=32
    rsrc = r.x;
    if (lane < deg) { rwx = __int_as_float(r.y); rwy = __int_as_float(r.z); }
  }

  float a0 = 0.f, a1 = 0.f, a2 = 0.f, a3 = 0.f;
  float a4 = 0.f, a5 = 0.f, a6 = 0.f, a7 = 0.f;

  const int npair = (deg + 1) >> 1;
  int i = 0;
  for (; i + 4 <= npair; i += 4) {
    const int j0 = 2 * i + half;
    const int s0 = __shfl(rsrc, j0);
    const int s1 = __shfl(rsrc, j0 + 2);
    const int s2 = __shfl(rsrc, j0 + 4);
    const int s3 = __shfl(rsrc, j0 + 6);
    const ushort4 u0 = *reinterpret_cast<const ushort4*>(xb + (s0 << 7) + c4);
    const ushort4 u1 = *reinterpret_cast<const ushort4*>(xb + (s1 << 7) + c4);
    const ushort4 u2 = *reinterpret_cast<const ushort4*>(xb + (s2 << 7) + c4);
    const ushort4 u3 = *reinterpret_cast<const ushort4*>(xb + (s3 << 7) + c4);
    const float w0x = __shfl(rwx, j0),     w0y = __shfl(rwy, j0);
    const float w1x = __shfl(rwx, j0 + 2), w1y = __shfl(rwy, j0 + 2);
    const float w2x = __shfl(rwx, j0 + 4), w2y = __shfl(rwy, j0 + 4);
    const float w3x = __shfl(rwx, j0 + 6), w3y = __shfl(rwy, j0 + 6);
    ACC8(bf2f(u0.x), bf2f(u0.y), bf2f(u0.z), bf2f(u0.w), w0x, w0y)
    ACC8(bf2f(u1.x), bf2f(u1.y), bf2f(u1.z), bf2f(u1.w), w1x, w1y)
    ACC8(bf2f(u2.x), bf2f(u2.y), bf2f(u2.z), bf2f(u2.w), w2x, w2y)
    ACC8(bf2f(u3.x), bf2f(u3.y), bf2f(u3.z), bf2f(u3.w), w3x, w3y)
  }
  for (; i < npair; ++i) {
    const int j = 2 * i + half;
    const int s0 = __shfl(rsrc, j);
    const ushort4 u0 = *reinterpret_cast<const ushort4*>(xb + (s0 << 7) + c4);
    const float w0x = __shfl(rwx, j), w0y = __shfl(rwy, j);
    ACC8(bf2f(u0.x), bf2f(u0.y), bf2f(u0.z), bf2f(u0.w), w0x, w0y)
  }

  // Sum of weights (zeros beyond deg): 64-lane butterfly.
  float swx = rwx, swy = rwy;
  for (int off = 1; off < 64; off <<= 1) {
    swx += __shfl_xor(swx, off);
    swy += __shfl_xor(swy, off);
  }

  // Fold half-wave partials (lanes c and c+32 share channels).
  a0 += __shfl_xor(a0, 32); a1 += __shfl_xor(a1, 32);
  a2 += __shfl_xor(a2, 32); a3 += __shfl_xor(a3, 32);
  a4 += __shfl_xor(a4, 32); a5 += __shfl_xor(a5, 32);
  a6 += __shfl_xor(a6, 32); a7 += __shfl_xor(a7, 32);

  // Overflow edges (deg > CAP, extremely rare): fold in exactly, f32.
  if (cnt > CAP) {
    const int novf = min(*ovfcnt, OVF_CAP);
    for (int k = 0; k < novf; ++k) {
      const int4 r = ovflist[k];
      if (r.x == node) {
        const float wx = __int_as_float(r.z), wy = __int_as_float(r.w);
        const float4 X = *reinterpret_cast<const float4*>(x + (r.y << 7) + c4);
        if (half == 0) {
          a0 = fmaf(wx, X.x, a0); a1 = fmaf(wy, X.x, a1);
          a2 = fmaf(wx, X.y, a2); a3 = fmaf(wy, X.y, a3);
        } else {
          a4 = fmaf(wx, X.z, a4); a5 = fmaf(wy, X.z, a5);
          a6 = fmaf(wx, X.w, a6); a7 = fmaf(wy, X.w, a7);
        }
        swx += wx; swy += wy;
      }
    }
  }

  float4 o;
  if (half == 0) {
    o.x = a0 - swx * xt.x; o.y = a1 - swy * xt.x;
    o.z = a2 - swx * xt.y; o.w = a3 - swy * xt.y;
  } else {
    o.x = a4 - swx * xt.z; o.y = a5 - swy * xt.z;
    o.z = a6 - swx * xt.w; o.w = a7 - swy * xt.w;
  }
  *reinterpret_cast<float4*>(out + (node << 8) + 8 * c + 4 * half) = o;
}

// ---------- f32 CAP=64 bucket fallback (R8 path) ----------
#define CAPF 64
__global__ __launch_bounds__(256) void k_append_f(const int* __restrict__ edges,
                                                  const float2* __restrict__ ew,
                                                  int* __restrict__ counts,
                                                  int4* __restrict__ rec, int E) {
  const int e = blockIdx.x * blockDim.x + threadIdx.x;
  if (e >= E) return;
  const int2 ts = reinterpret_cast<const int2*>(edges)[e];
  const float2 w = ew[e];
  const int pos = atomicAdd(&counts[ts.x], 1);
  if (pos < CAPF) {
    int4 r;
    r.x = ts.y; r.y = __float_as_int(w.x); r.z = __float_as_int(w.y); r.w = 0;
    rec[(size_t)ts.x * CAPF + pos] = r;
  }
}

#define ACCF(X, WX, WY)                                   \
  a0 = fmaf((WX), (X).x, a0); a1 = fmaf((WY), (X).x, a1); \
  a2 = fmaf((WX), (X).y, a2); a3 = fmaf((WY), (X).y, a3); \
  a4 = fmaf((WX), (X).z, a4); a5 = fmaf((WY), (X).z, a5); \
  a6 = fmaf((WX), (X).w, a6); a7 = fmaf((WY), (X).w, a7);

__global__ __launch_bounds__(256) void k_gather3(const float* __restrict__ x,
                                                 const int* __restrict__ counts,
                                                 const int4* __restrict__ rec,
                                                 float* __restrict__ out, int n) {
  const int lane = threadIdx.x & 63;
  const int node = (blockIdx.x * blockDim.x + threadIdx.x) >> 6;
  if (node >= n) return;
  const int c = lane & 31;
  const int half = lane >> 5;
  const int deg = min(counts[node], CAPF);
  const float4 xt = *reinterpret_cast<const float4*>(x + (size_t)node * 128 + 4 * c);
  int rsrc = 0; float rwx = 0.f, rwy = 0.f;
  if (deg > 0) {
    const int li = min(lane, deg - 1);
    const int4 r = rec[(size_t)node * CAPF + li];
    rsrc = r.x;
    if (lane < deg) { rwx = __int_as_float(r.y); rwy = __int_as_float(r.z); }
  }
  float a0 = 0.f, a1 = 0.f, a2 = 0.f, a3 = 0.f;
  float a4 = 0.f, a5 = 0.f, a6 = 0.f, a7 = 0.f;
  const int npair = (deg + 1) >> 1;
  for (int i = 0; i < npair; ++i) {
    const int j = 2 * i + half;
    const int s0 = __shfl(rsrc, j);
    const float4 X = *reinterpret_cast<const float4*>(x + (size_t)s0 * 128 + 4 * c);
    const float wx = __shfl(rwx, j), wy = __shfl(rwy, j);
    ACCF(X, wx, wy)
  }
  float swx = rwx, swy = rwy;
  for (int off = 1; off < 64; off <<= 1) {
    swx += __shfl_xor(swx, off);
    swy += __shfl_xor(swy, off);
  }
  a0 += __shfl_xor(a0, 32); a1 += __shfl_xor(a1, 32);
  a2 += __shfl_xor(a2, 32); a3 += __shfl_xor(a3, 32);
  a4 += __shfl_xor(a4, 32); a5 += __shfl_xor(a5, 32);
  a6 += __shfl_xor(a6, 32); a7 += __shfl_xor(a7, 32);
  float4 o;
  if (half == 0) {
    o.x = a0 - swx * xt.x; o.y = a1 - swy * xt.x;
    o.z = a2 - swx * xt.y; o.w = a3 - swy * xt.y;
  } else {
    o.x = a4 - swx * xt.z; o.y = a5 - swy * xt.z;
    o.z = a6 - swx * xt.w; o.w = a7 - swy * xt.w;
  }
  *reinterpret_cast<float4*>(out + (size_t)node * 256 + 8 * c + 4 * half) = o;
}

// ---------- atomic fallback ----------
__global__ __launch_bounds__(256) void k_atomic(const float* __restrict__ x,
                                                const float* __restrict__ ew,
                                                const int* __restrict__ edges,
                                                float* __restrict__ out, int E) {
  const int lane = threadIdx.x & 63;
  const int wave = (blockIdx.x * blockDim.x + threadIdx.x) >> 6;
  const int nwaves = (gridDim.x * blockDim.x) >> 6;
  for (int e = wave; e < E; e += nwaves) {
    const int2 ts = *reinterpret_cast<const int2*>(edges + 2ll * e);
    const float2 w = *reinterpret_cast<const float2*>(ew + 2ll * e);
    const float2 vs = *reinterpret_cast<const float2*>(x + (size_t)ts.y * 128 + 2 * lane);
    const float2 vt = *reinterpret_cast<const float2*>(x + (size_t)ts.x * 128 + 2 * lane);
    const float d0 = vs.x - vt.x;
    const float d1 = vs.y - vt.y;
    float* o = out + (size_t)ts.x * 256 + 4 * lane;
    unsafeAtomicAdd(o + 0, w.x * d0);
    unsafeAtomicAdd(o + 1, w.y * d0);
    unsafeAtomicAdd(o + 2, w.x * d1);
    unsafeAtomicAdd(o + 3, w.y * d1);
  }
}

extern "C" void kernel_launch(void* const* d_in, const int* in_sizes, int n_in,
                              void* d_out, int out_size, void* d_ws, size_t ws_size,
                              hipStream_t stream) {
  const float* x = (const float*)d_in[0];
  const float* ewf = (const float*)d_in[1];
  const int* edges = (const int*)d_in[2];
  float* out = (float*)d_out;
  const float2* ew = (const float2*)ewf;

  const int E = in_sizes[1] / 2;    // edge_weights: [E,2]
  const int N = in_sizes[0] / 128;  // x: [N,128]

  // Layout: counts[N]+ovfcnt | xb[N*128] u16 | rec[N*CAP] int4 | ovflist int4
  size_t cnt_sec = ((size_t)(N + 1) * 4 + 255) & ~(size_t)255;
  size_t xb_sec = ((size_t)N * 128 * 2 + 255) & ~(size_t)255;
  size_t rec_sec = (size_t)N * CAP * 16;
  size_t need_bf16 = cnt_sec + xb_sec + rec_sec + (size_t)OVF_CAP * 16;
  size_t need_f32 = cnt_sec + (size_t)N * CAPF * 16;

  char* wsb = (char*)d_ws;

  // 32-bit-indexing safety: N*256 (out), N*CAP*4 (rec idx), N*128 all < 2^31.
  if (ws_size >= need_bf16 && (E & 1) == 0 && N <= 4000000) {
    int* counts = (int*)wsb;
    int* ovfcnt = counts + N;
    u16* xb = (u16*)(wsb + cnt_sec);
    int4* rec = (int4*)(wsb + cnt_sec + xb_sec);
    int4* ovflist = (int4*)(wsb + cnt_sec + xb_sec + rec_sec);
    hipMemsetAsync(counts, 0, (size_t)(N + 1) * 4, stream);
    // NAPP append blocks + 1024 cvt blocks
    k_prep<<<NAPP + 1024, 256, 0, stream>>>(edges, ewf, x, counts, rec, ovfcnt,
                                            ovflist, xb, E, N, N * 128 / 4);
    k_gather5<<<(N * 64 + 255) / 256, 256, 0, stream>>>(x, xb, counts, rec,
                                                        ovfcnt, ovflist, out, N);
    return;
  }

  if (ws_size >= need_f32) {
    int* counts = (int*)wsb;
    int4* rec = (int4*)(wsb + cnt_sec);
    hipMemsetAsync(counts, 0, (size_t)N * 4, stream);
    k_append_f<<<(E + 255) / 256, 256, 0, stream>>>(edges, ew, counts, rec, E);
    k_gather3<<<(N * 64 + 255) / 256, 256, 0, stream>>>(x, counts, rec, out, N);
    return;
  }

  hipMemsetAsync(d_out, 0, (size_t)out_size * sizeof(float), stream);
  k_atomic<<<2048, 256, 0, stream>>>(x, ewf, edges, out, E);
}

// Round 20
// 95.141 us; speedup vs baseline: 1.0711x; 1.0711x over previous
//
#include <hip/hip_runtime.h>

// GradientConv: out[tgt, c*2+d] += ew[e,d] * (x[src,c] - x[tgt,c])
// B=1, N=50000, C=128, E=800000, D=2
//
// Pipeline (3 dispatches) [R18 config = measured best, 95.5us]:
//   1) memset counts
//   2) k_prep: fused {XCD-partitioned append (blocks 0..NAPP-1, partition =
//      blockIdx&7 -> XCD round-robin)} + {x->bf16 cvt (remaining blocks)}
//   3) k_gather5: one wave per node, 32-bit indexing, 4-tier unroll,
//        out[t] = sum_e w_e (x) xb[src_e] - (sum_e w_e) (x) x[t]
//      rec load clamped to lanes 0-31 (shfl only reads lanes<32) -> halves
//      rec fetch; overflow (deg>CAP) folded in-register (exact f32).
// Fallbacks: f32 CAP=64 bucket path, atomics.

#define CAP 32
#define OVF_CAP 65536
#define NPART 8
#define NAPP 3328  // append blocks: 8 partitions x 416

typedef unsigned short u16;
typedef unsigned int u32;

__device__ __forceinline__ u16 f2bf(float f) {
  u32 u = __float_as_uint(f);
  return (u16)((u + 0x7FFFu + ((u >> 16) & 1u)) >> 16);
}
__device__ __forceinline__ float bf2f(u16 v) {
  return __uint_as_float(((u32)v) << 16);
}

__device__ __forceinline__ void append_one(int tgt, int src, float wx, float wy,
                                           int* counts, int4* rec,
                                           int* ovfcnt, int4* ovflist) {
  const int pos = atomicAdd(&counts[tgt], 1);
  if (pos < CAP) {
    int4 r;
    r.x = src; r.y = __float_as_int(wx); r.z = __float_as_int(wy); r.w = 0;
    rec[tgt * CAP + pos] = r;
  } else {
    const int op = atomicAdd(ovfcnt, 1);
    if (op < OVF_CAP) {
      int4 r;
      r.x = tgt; r.y = src; r.z = __float_as_int(wx); r.w = __float_as_int(wy);
      ovflist[op] = r;
    }
  }
}

// ---------- fused append (XCD-partitioned) + x->bf16 cvt ----------
__global__ __launch_bounds__(256) void k_prep(const int* __restrict__ edges,
                                              const float* __restrict__ ew,
                                              const float* __restrict__ x,
                                              int* __restrict__ counts,
                                              int4* __restrict__ rec,
                                              int* __restrict__ ovfcnt,
                                              int4* __restrict__ ovflist,
                                              u16* __restrict__ xb,
                                              int E, int N, int total4) {
  if (blockIdx.x < NAPP) {
    // ---- append: partition = blockIdx&7 tracks XCD round-robin ----
    const int part = blockIdx.x & (NPART - 1);
    const int bidx = blockIdx.x >> 3;
    const int nblk = NAPP >> 3;
    const int lo = (int)((long long)part * N / NPART);
    const int hi = (int)((long long)(part + 1) * N / NPART);
    const int npairs = E >> 1;  // E even (guarded on host)
    const int stride = nblk * blockDim.x;
    for (int i = bidx * blockDim.x + threadIdx.x; i < npairs; i += stride) {
      const int4 p = reinterpret_cast<const int4*>(edges)[i];  // t0,s0,t1,s1
      const bool in0 = (p.x >= lo) & (p.x < hi);
      const bool in1 = (p.z >= lo) & (p.z < hi);
      if (in0 | in1) {
        const float4 w = reinterpret_cast<const float4*>(ew)[i];
        if (in0) append_one(p.x, p.y, w.x, w.y, counts, rec, ovfcnt, ovflist);
        if (in1) append_one(p.z, p.w, w.z, w.w, counts, rec, ovfcnt, ovflist);
      }
    }
  } else {
    // ---- cvt: grid-stride over x in float4 units ----
    const int nb = gridDim.x - NAPP;
    const int stride = nb * blockDim.x;
    for (int i = (blockIdx.x - NAPP) * blockDim.x + threadIdx.x; i < total4;
         i += stride) {
      const float4 v = reinterpret_cast<const float4*>(x)[i];
      ushort4 o;
      o.x = f2bf(v.x); o.y = f2bf(v.y); o.z = f2bf(v.z); o.w = f2bf(v.w);
      reinterpret_cast<ushort4*>(xb)[i] = o;
    }
  }
}

#define ACC8(X0, X1, X2, X3, WX, WY)                    \
  a0 = fmaf((WX), (X0), a0); a1 = fmaf((WY), (X0), a1); \
  a2 = fmaf((WX), (X1), a2); a3 = fmaf((WY), (X1), a3); \
  a4 = fmaf((WX), (X2), a4); a5 = fmaf((WY), (X2), a5); \
  a6 = fmaf((WX), (X3), a6); a7 = fmaf((WY), (X3), a7);

// One wave per node; c=lane&31 covers channels 4c..4c+3; half-wave processes
// even/odd edge indices. ALL indexing 32-bit -> saddr+voffset loads.
__global__ __launch_bounds__(256) void k_gather5(const float* __restrict__ x,
                                                 const u16* __restrict__ xb,
                                                 const int* __restrict__ counts,
                                                 const int4* __restrict__ rec,
                                                 const int* __restrict__ ovfcnt,
                                                 const int4* __restrict__ ovflist,
                                                 float* __restrict__ out, int n) {
  const int lane = threadIdx.x & 63;
  const int node = (blockIdx.x * blockDim.x + threadIdx.x) >> 6;
  if (node >= n) return;
  const int c = lane & 31;
  const int half = lane >> 5;
  const int c4 = 4 * c;

  const int cnt = counts[node];
  const int deg = min(cnt, CAP);

  // xt early (independent f32 load for exact -sum(w)*x[t]).
  const float4 xt = *reinterpret_cast<const float4*>(x + (node << 7) + c4);

  int rsrc = 0;
  float rwx = 0.f, rwy = 0.f;
  if (deg > 0) {
    // Inner loop only shfls from lanes 0-31 (npair <= 16 => j < 32), so
    // lanes 32-63 duplicate lanes 0-31's addresses (coalesced broadcast,
    // halves rec fetch). Weights stay 0 for lane >= deg -> butterfly exact.
    const int li = min(lane & 31, deg - 1);
    const int4 r = rec[(node << 5) + li];  // CAP=32
    rsrc = r.x;
    if (lane < deg) { rwx = __int_as_float(r.y); rwy = __int_as_float(r.z); }
  }

  float a0 = 0.f, a1 = 0.f, a2 = 0.f, a3 = 0.f;
  float a4 = 0.f, a5 = 0.f, a6 = 0.f, a7 = 0.f;

  const int npair = (deg + 1) >> 1;
  int i = 0;
  for (; i + 4 <= npair; i += 4) {
    const int j0 = 2 * i + half;
    const int s0 = __shfl(rsrc, j0);
    const int s1 = __shfl(rsrc, j0 + 2);
    const int s2 = __shfl(rsrc, j0 + 4);
    const int s3 = __shfl(rsrc, j0 + 6);
    const ushort4 u0 = *reinterpret_cast<const ushort4*>(xb + (s0 << 7) + c4);
    const ushort4 u1 = *reinterpret_cast<const ushort4*>(xb + (s1 << 7) + c4);
    const ushort4 u2 = *reinterpret_cast<const ushort4*>(xb + (s2 << 7) + c4);
    const ushort4 u3 = *reinterpret_cast<const ushort4*>(xb + (s3 << 7) + c4);
    const float w0x = __shfl(rwx, j0),     w0y = __shfl(rwy, j0);
    const float w1x = __shfl(rwx, j0 + 2), w1y = __shfl(rwy, j0 + 2);
    const float w2x = __shfl(rwx, j0 + 4), w2y = __shfl(rwy, j0 + 4);
    const float w3x = __shfl(rwx, j0 + 6), w3y = __shfl(rwy, j0 + 6);
    ACC8(bf2f(u0.x), bf2f(u0.y), bf2f(u0.z), bf2f(u0.w), w0x, w0y)
    ACC8(bf2f(u1.x), bf2f(u1.y), bf2f(u1.z), bf2f(u1.w), w1x, w1y)
    ACC8(bf2f(u2.x), bf2f(u2.y), bf2f(u2.z), bf2f(u2.w), w2x, w2y)
    ACC8(bf2f(u3.x), bf2f(u3.y), bf2f(u3.z), bf2f(u3.w), w3x, w3y)
  }
  for (; i < npair; ++i) {
    const int j = 2 * i + half;
    const int s0 = __shfl(rsrc, j);
    const ushort4 u0 = *reinterpret_cast<const ushort4*>(xb + (s0 << 7) + c4);
    const float w0x = __shfl(rwx, j), w0y = __shfl(rwy, j);
    ACC8(bf2f(u0.x), bf2f(u0.y), bf2f(u0.z), bf2f(u0.w), w0x, w0y)
  }

  // Sum of weights (zeros beyond deg): 64-lane butterfly.
  float swx = rwx, swy = rwy;
  for (int off = 1; off < 64; off <<= 1) {
    swx += __shfl_xor(swx, off);
    swy += __shfl_xor(swy, off);
  }

  // Fold half-wave partials (lanes c and c+32 share channels).
  a0 += __shfl_xor(a0, 32); a1 += __shfl_xor(a1, 32);
  a2 += __shfl_xor(a2, 32); a3 += __shfl_xor(a3, 32);
  a4 += __shfl_xor(a4, 32); a5 += __shfl_xor(a5, 32);
  a6 += __shfl_xor(a6, 32); a7 += __shfl_xor(a7, 32);

  // Overflow edges (deg > CAP, extremely rare): fold in exactly, f32.
  if (cnt > CAP) {
    const int novf = min(*ovfcnt, OVF_CAP);
    for (int k = 0; k < novf; ++k) {
      const int4 r = ovflist[k];
      if (r.x == node) {
        const float wx = __int_as_float(r.z), wy = __int_as_float(r.w);
        const float4 X = *reinterpret_cast<const float4*>(x + (r.y << 7) + c4);
        if (half == 0) {
          a0 = fmaf(wx, X.x, a0); a1 = fmaf(wy, X.x, a1);
          a2 = fmaf(wx, X.y, a2); a3 = fmaf(wy, X.y, a3);
        } else {
          a4 = fmaf(wx, X.z, a4); a5 = fmaf(wy, X.z, a5);
          a6 = fmaf(wx, X.w, a6); a7 = fmaf(wy, X.w, a7);
        }
        swx += wx; swy += wy;
      }
    }
  }

  float4 o;
  if (half == 0) {
    o.x = a0 - swx * xt.x; o.y = a1 - swy * xt.x;
    o.z = a2 - swx * xt.y; o.w = a3 - swy * xt.y;
  } else {
    o.x = a4 - swx * xt.z; o.y = a5 - swy * xt.z;
    o.z = a6 - swx * xt.w; o.w = a7 - swy * xt.w;
  }
  *reinterpret_cast<float4*>(out + (node << 8) + 8 * c + 4 * half) = o;
}

// ---------- f32 CAP=64 bucket fallback (R8 path) ----------
#define CAPF 64
__global__ __launch_bounds__(256) void k_append_f(const int* __restrict__ edges,
                                                  const float2* __restrict__ ew,
                                                  int* __restrict__ counts,
                                                  int4* __restrict__ rec, int E) {
  const int e = blockIdx.x * blockDim.x + threadIdx.x;
  if (e >= E) return;
  const int2 ts = reinterpret_cast<const int2*>(edges)[e];
  const float2 w = ew[e];
  const int pos = atomicAdd(&counts[ts.x], 1);
  if (pos < CAPF) {
    int4 r;
    r.x = ts.y; r.y = __float_as_int(w.x); r.z = __float_as_int(w.y); r.w = 0;
    rec[(size_t)ts.x * CAPF + pos] = r;
  }
}

#define ACCF(X, WX, WY)                                   \
  a0 = fmaf((WX), (X).x, a0); a1 = fmaf((WY), (X).x, a1); \
  a2 = fmaf((WX), (X).y, a2); a3 = fmaf((WY), (X).y, a3); \
  a4 = fmaf((WX), (X).z, a4); a5 = fmaf((WY), (X).z, a5); \
  a6 = fmaf((WX), (X).w, a6); a7 = fmaf((WY), (X).w, a7);

__global__ __launch_bounds__(256) void k_gather3(const float* __restrict__ x,
                                                 const int* __restrict__ counts,
                                                 const int4* __restrict__ rec,
                                                 float* __restrict__ out, int n) {
  const int lane = threadIdx.x & 63;
  const int node = (blockIdx.x * blockDim.x + threadIdx.x) >> 6;
  if (node >= n) return;
  const int c = lane & 31;
  const int half = lane >> 5;
  const int deg = min(counts[node], CAPF);
  const float4 xt = *reinterpret_cast<const float4*>(x + (size_t)node * 128 + 4 * c);
  int rsrc = 0; float rwx = 0.f, rwy = 0.f;
  if (deg > 0) {
    const int li = min(lane, deg - 1);
    const int4 r = rec[(size_t)node * CAPF + li];
    rsrc = r.x;
    if (lane < deg) { rwx = __int_as_float(r.y); rwy = __int_as_float(r.z); }
  }
  float a0 = 0.f, a1 = 0.f, a2 = 0.f, a3 = 0.f;
  float a4 = 0.f, a5 = 0.f, a6 = 0.f, a7 = 0.f;
  const int npair = (deg + 1) >> 1;
  for (int i = 0; i < npair; ++i) {
    const int j = 2 * i + half;
    const int s0 = __shfl(rsrc, j);
    const float4 X = *reinterpret_cast<const float4*>(x + (size_t)s0 * 128 + 4 * c);
    const float wx = __shfl(rwx, j), wy = __shfl(rwy, j);
    ACCF(X, wx, wy)
  }
  float swx = rwx, swy = rwy;
  for (int off = 1; off < 64; off <<= 1) {
    swx += __shfl_xor(swx, off);
    swy += __shfl_xor(swy, off);
  }
  a0 += __shfl_xor(a0, 32); a1 += __shfl_xor(a1, 32);
  a2 += __shfl_xor(a2, 32); a3 += __shfl_xor(a3, 32);
  a4 += __shfl_xor(a4, 32); a5 += __shfl_xor(a5, 32);
  a6 += __shfl_xor(a6, 32); a7 += __shfl_xor(a7, 32);
  float4 o;
  if (half == 0) {
    o.x = a0 - swx * xt.x; o.y = a1 - swy * xt.x;
    o.z = a2 - swx * xt.y; o.w = a3 - swy * xt.y;
  } else {
    o.x = a4 - swx * xt.z; o.y = a5 - swy * xt.z;
    o.z = a6 - swx * xt.w; o.w = a7 - swy * xt.w;
  }
  *reinterpret_cast<float4*>(out + (size_t)node * 256 + 8 * c + 4 * half) = o;
}

// ---------- atomic fallback ----------
__global__ __launch_bounds__(256) void k_atomic(const float* __restrict__ x,
                                                const float* __restrict__ ew,
                                                const int* __restrict__ edges,
                                                float* __restrict__ out, int E) {
  const int lane = threadIdx.x & 63;
  const int wave = (blockIdx.x * blockDim.x + threadIdx.x) >> 6;
  const int nwaves = (gridDim.x * blockDim.x) >> 6;
  for (int e = wave; e < E; e += nwaves) {
    const int2 ts = *reinterpret_cast<const int2*>(edges + 2ll * e);
    const float2 w = *reinterpret_cast<const float2*>(ew + 2ll * e);
    const float2 vs = *reinterpret_cast<const float2*>(x + (size_t)ts.y * 128 + 2 * lane);
    const float2 vt = *reinterpret_cast<const float2*>(x + (size_t)ts.x * 128 + 2 * lane);
    const float d0 = vs.x - vt.x;
    const float d1 = vs.y - vt.y;
    float* o = out + (size_t)ts.x * 256 + 4 * lane;
    unsafeAtomicAdd(o + 0, w.x * d0);
    unsafeAtomicAdd(o + 1, w.y * d0);
    unsafeAtomicAdd(o + 2, w.x * d1);
    unsafeAtomicAdd(o + 3, w.y * d1);
  }
}

extern "C" void kernel_launch(void* const* d_in, const int* in_sizes, int n_in,
                              void* d_out, int out_size, void* d_ws, size_t ws_size,
                              hipStream_t stream) {
  const float* x = (const float*)d_in[0];
  const float* ewf = (const float*)d_in[1];
  const int* edges = (const int*)d_in[2];
  float* out = (float*)d_out;
  const float2* ew = (const float2*)ewf;

  const int E = in_sizes[1] / 2;    // edge_weights: [E,2]
  const int N = in_sizes[0] / 128;  // x: [N,128]

  // Layout: counts[N]+ovfcnt | xb[N*128] u16 | rec[N*CAP] int4 | ovflist int4
  size_t cnt_sec = ((size_t)(N + 1) * 4 + 255) & ~(size_t)255;
  size_t xb_sec = ((size_t)N * 128 * 2 + 255) & ~(size_t)255;
  size_t rec_sec = (size_t)N * CAP * 16;
  size_t need_bf16 = cnt_sec + xb_sec + rec_sec + (size_t)OVF_CAP * 16;
  size_t need_f32 = cnt_sec + (size_t)N * CAPF * 16;

  char* wsb = (char*)d_ws;

  // 32-bit-indexing safety: N*256 (out), N*CAP*4 (rec idx), N*128 all < 2^31.
  if (ws_size >= need_bf16 && (E & 1) == 0 && N <= 4000000) {
    int* counts = (int*)wsb;
    int* ovfcnt = counts + N;
    u16* xb = (u16*)(wsb + cnt_sec);
    int4* rec = (int4*)(wsb + cnt_sec + xb_sec);
    int4* ovflist = (int4*)(wsb + cnt_sec + xb_sec + rec_sec);
    hipMemsetAsync(counts, 0, (size_t)(N + 1) * 4, stream);
    // NAPP append blocks + 1024 cvt blocks
    k_prep<<<NAPP + 1024, 256, 0, stream>>>(edges, ewf, x, counts, rec, ovfcnt,
                                            ovflist, xb, E, N, N * 128 / 4);
    k_gather5<<<(N * 64 + 255) / 256, 256, 0, stream>>>(x, xb, counts, rec,
                                                        ovfcnt, ovflist, out, N);
    return;
  }

  if (ws_size >= need_f32) {
    int* counts = (int*)wsb;
    int4* rec = (int4*)(wsb + cnt_sec);
    hipMemsetAsync(counts, 0, (size_t)N * 4, stream);
    k_append_f<<<(E + 255) / 256, 256, 0, stream>>>(edges, ew, counts, rec, E);
    k_gather3<<<(N * 64 + 255) / 256, 256, 0, stream>>>(x, counts, rec, out, N);
    return;
  }

  hipMemsetAsync(d_out, 0, (size_t)out_size * sizeof(float), stream);
  k_atomic<<<2048, 256, 0, stream>>>(x, ewf, edges, out, E);
}